// Round 1
// baseline (1057.993 us; speedup 1.0000x reference)
//
#include <hip/hip_runtime.h>
#include <stdint.h>

#define BSZ 8
#define SEQ 2048
#define DM 1024
#define DS 16
#define MROWS (BSZ * SEQ)  // 16384

typedef __bf16 bf16x8 __attribute__((ext_vector_type(8)));
typedef float f32x4 __attribute__((ext_vector_type(4)));

union F4 { float4 v; float f[4]; };

// round-to-nearest-even fp32 -> bf16 (bit pattern)
__device__ __forceinline__ uint16_t f2bf(float f) {
  uint32_t u = __float_as_uint(f);
  u += 0x7FFFu + ((u >> 16) & 1u);
  return (uint16_t)(u >> 16);
}

// async global->LDS, 16B per lane; LDS base must be wave-uniform.
__device__ __forceinline__ void async_cp16(const void* g, void* l) {
  __builtin_amdgcn_global_load_lds(
      (const __attribute__((address_space(1))) uint32_t*)(uintptr_t)g,
      (__attribute__((address_space(3))) uint32_t*)(uint32_t)(uintptr_t)l,
      16, 0, 0);
}

// ---------------- dt_w fp32 -> bf16 ----------------
__global__ __launch_bounds__(256) void wprep_kernel(
    const float* __restrict__ w, uint16_t* __restrict__ wb) {
  int t = blockIdx.x * 256 + threadIdx.x;  // DM*DM/4 threads
  F4 u; u.v = *(const float4*)(w + (size_t)t * 4);
  uint32_t lo = f2bf(u.f[0]) | ((uint32_t)f2bf(u.f[1]) << 16);
  uint32_t hi = f2bf(u.f[2]) | ((uint32_t)f2bf(u.f[3]) << 16);
  *(uint2*)(wb + (size_t)t * 4) = make_uint2(lo, hi);
}

// ---------------- depthwise conv k=3 pad=1 -> bf16 xf ----------------
__global__ __launch_bounds__(256) void conv_kernel(
    const float* __restrict__ x, const float* __restrict__ cw,
    const float* __restrict__ cb, uint16_t* __restrict__ xf) {
  int t = blockIdx.x * 256 + threadIdx.x;  // MROWS*DM/4 threads
  int cg = t & (DM / 4 - 1);
  int bn = t >> 8;
  int n = bn & (SEQ - 1);
  int c0 = cg * 4;
  const float* row = x + (size_t)bn * DM + c0;
  F4 xm, xc, xp;
  xm.v = make_float4(0.f, 0.f, 0.f, 0.f);
  xp.v = make_float4(0.f, 0.f, 0.f, 0.f);
  xc.v = *(const float4*)row;
  if (n > 0)       xm.v = *(const float4*)(row - DM);
  if (n < SEQ - 1) xp.v = *(const float4*)(row + DM);
  uint16_t o[4];
#pragma unroll
  for (int j = 0; j < 4; ++j) {
    int c = c0 + j;
    float v = cw[c * 3 + 0] * xm.f[j] + cw[c * 3 + 1] * xc.f[j] +
              cw[c * 3 + 2] * xp.f[j] + cb[c];
    o[j] = f2bf(v);
  }
  uint32_t lo = o[0] | ((uint32_t)o[1] << 16);
  uint32_t hi = o[2] | ((uint32_t)o[3] << 16);
  *(uint2*)(xf + (size_t)bn * DM + c0) = make_uint2(lo, hi);
}

// ---------------- dt = sigmoid(xf @ dt_w^T + dt_b)*0.099 + 0.001 ----------------
// NT GEMM, 128x128 tile, BK=64, 4 waves in 2x2, 16x16x32 bf16 MFMA.
__global__ __launch_bounds__(256) void gemm_kernel(
    const uint16_t* __restrict__ A,   // MROWS x DM bf16 (xf)
    const uint16_t* __restrict__ B,   // DM x DM bf16 (dt_w, row j, contiguous k)
    const float* __restrict__ bias,   // DM (dt_b)
    float* __restrict__ dt) {         // MROWS x DM f32
  __shared__ __align__(16) uint16_t As[128 * 64];
  __shared__ __align__(16) uint16_t Bs[128 * 64];
  const int tid = threadIdx.x;
  const int w = tid >> 6;
  const int L = tid & 63;
  const int wm = w & 1, wn = w >> 1;
  const int lane15 = L & 15, q = L >> 4;
  const int m0 = blockIdx.y * 128;
  const int n0 = blockIdx.x * 128;
  const int lr = L >> 3;        // row-in-8 for staging
  const int lc = (L & 7) * 8;   // k-col offset for staging (8 bf16 = 16B)

  f32x4 acc[4][4] = {};

  for (int kt = 0; kt < DM; kt += 64) {
#pragma unroll
    for (int r = 0; r < 4; ++r) {
      int R = (r * 4 + w) * 8;  // wave-uniform LDS base
      async_cp16(A + (size_t)(m0 + R + lr) * DM + kt + lc, &As[R * 64]);
    }
#pragma unroll
    for (int r = 0; r < 4; ++r) {
      int R = (r * 4 + w) * 8;
      async_cp16(B + (size_t)(n0 + R + lr) * DM + kt + lc, &Bs[R * 64]);
    }
    __syncthreads();  // drains vmcnt -> LDS tiles visible
#pragma unroll
    for (int ks = 0; ks < 64; ks += 32) {
      bf16x8 af[4], bfr[4];
#pragma unroll
      for (int mi = 0; mi < 4; ++mi)
        af[mi] = *(const bf16x8*)(As + (wm * 64 + mi * 16 + lane15) * 64 + ks + q * 8);
#pragma unroll
      for (int ni = 0; ni < 4; ++ni)
        bfr[ni] = *(const bf16x8*)(Bs + (wn * 64 + ni * 16 + lane15) * 64 + ks + q * 8);
#pragma unroll
      for (int mi = 0; mi < 4; ++mi)
#pragma unroll
        for (int ni = 0; ni < 4; ++ni)
          acc[mi][ni] = __builtin_amdgcn_mfma_f32_16x16x32_bf16(
              af[mi], bfr[ni], acc[mi][ni], 0, 0, 0);
    }
    __syncthreads();
  }

  // epilogue: D layout col=lane&15, row=q*4+reg
#pragma unroll
  for (int ni = 0; ni < 4; ++ni) {
    int col = n0 + wn * 64 + ni * 16 + lane15;
    float db = bias[col];
#pragma unroll
    for (int mi = 0; mi < 4; ++mi) {
      int rowb = m0 + wm * 64 + mi * 16 + q * 4;
#pragma unroll
      for (int r = 0; r < 4; ++r) {
        float z = acc[mi][ni][r] + db;
        float s = 0.099f / (1.f + __expf(-z)) + 0.001f;
        dt[(size_t)(rowb + r) * DM + col] = s;
      }
    }
  }
}

// ---------------- sequential selective scan ----------------
// lane = (c_sub*16 + d); one wave = 4 channels x 16 states; conv recomputed
// in fp32 via rolling registers; y = sum_d s*c via 4x shfl_xor.
__global__ __launch_bounds__(64) void scan_kernel(
    const float* __restrict__ x, const float* __restrict__ dt,
    const float* __restrict__ a_log, const float* __restrict__ bm,
    const float* __restrict__ cm, const float* __restrict__ cw,
    const float* __restrict__ cb, float* __restrict__ out) {
  const int L = threadIdx.x;
  const int d = L & 15;
  const int ci = L >> 4;
  const int b = blockIdx.x >> 8;              // /(DM/4)
  const int cg = blockIdx.x & (DM / 4 - 1);
  const int c = cg * 4 + ci;

  const float Av = -log1pf(__expf(a_log[c * DS + d]));
  const float bv = bm[c * DS + d];
  const float cv = cm[c * DS + d];
  const float w0 = cw[c * 3 + 0], w1 = cw[c * 3 + 1], w2 = cw[c * 3 + 2];
  const float cbv = cb[c];

  const float* xp = x + (size_t)b * SEQ * DM + c;
  const float* dp = dt + (size_t)b * SEQ * DM + c;
  float* op = out + (size_t)b * SEQ * DM + c;

  float xm1 = 0.f;
  float x0 = xp[0];
  float x1 = xp[DM];
  float dcur = dp[0];
  float s = 0.f;

#pragma unroll 4
  for (int n = 0; n < SEQ; ++n) {
    float xnext = 0.f, dnext = 0.f;
    if (n + 2 < SEQ) xnext = xp[(size_t)(n + 2) * DM];
    if (n + 1 < SEQ) dnext = dp[(size_t)(n + 1) * DM];
    float xf = w0 * xm1 + w1 * x0 + w2 * x1 + cbv;
    float e = __expf(dcur * Av);
    s = e * s + (dcur * xf) * bv;
    float y = s * cv;
    y += __shfl_xor(y, 1, 64);
    y += __shfl_xor(y, 2, 64);
    y += __shfl_xor(y, 4, 64);
    y += __shfl_xor(y, 8, 64);
    if (d == 0) op[(size_t)n * DM] = y;
    xm1 = x0; x0 = x1; x1 = xnext; dcur = dnext;
  }
}

extern "C" void kernel_launch(void* const* d_in, const int* in_sizes, int n_in,
                              void* d_out, int out_size, void* d_ws, size_t ws_size,
                              hipStream_t stream) {
  const float* x     = (const float*)d_in[0];
  const float* a_log = (const float*)d_in[1];
  const float* bm    = (const float*)d_in[2];
  const float* cm    = (const float*)d_in[3];
  const float* dt_w  = (const float*)d_in[4];
  const float* dt_b  = (const float*)d_in[5];
  const float* cw    = (const float*)d_in[6];
  const float* cb    = (const float*)d_in[7];
  float* out = (float*)d_out;

  char* ws = (char*)d_ws;
  uint16_t* xf_bf = (uint16_t*)ws;                                       // 32 MB
  uint16_t* w_bf  = (uint16_t*)(ws + (size_t)MROWS * DM * 2);            // 2 MB
  float* dt = (float*)(ws + (size_t)MROWS * DM * 2 + (size_t)DM * DM * 2);  // 64 MB

  hipLaunchKernelGGL(wprep_kernel, dim3(DM * DM / 1024), dim3(256), 0, stream,
                     dt_w, w_bf);
  hipLaunchKernelGGL(conv_kernel, dim3(MROWS * DM / 1024), dim3(256), 0, stream,
                     x, cw, cb, xf_bf);
  hipLaunchKernelGGL(gemm_kernel, dim3(DM / 128, MROWS / 128), dim3(256), 0,
                     stream, xf_bf, w_bf, dt_b, dt);
  hipLaunchKernelGGL(scan_kernel, dim3(BSZ * DM / 4), dim3(64), 0, stream,
                     x, dt, a_log, bm, cm, cw, cb, out);
}

// Round 2
// 351.327 us; speedup vs baseline: 3.0114x; 3.0114x over previous
//
#include <hip/hip_runtime.h>
#include <stdint.h>

#define BSZ 8
#define SEQ 2048
#define DM 1024
#define DS 16
#define MROWS (BSZ * SEQ)  // 16384
#define CHK 32             // chunks over SEQ
#define CLEN (SEQ / CHK)   // 64 steps per chunk

typedef __bf16 bf16x8 __attribute__((ext_vector_type(8)));
typedef float f32x4 __attribute__((ext_vector_type(4)));

union F4 { float4 v; float f[4]; };

// round-to-nearest-even fp32 -> bf16 (bit pattern)
__device__ __forceinline__ uint16_t f2bf(float f) {
  uint32_t u = __float_as_uint(f);
  u += 0x7FFFu + ((u >> 16) & 1u);
  return (uint16_t)(u >> 16);
}

// async global->LDS, 16B per lane; LDS base must be wave-uniform.
__device__ __forceinline__ void async_cp16(const void* g, void* l) {
  __builtin_amdgcn_global_load_lds(
      (const __attribute__((address_space(1))) uint32_t*)(uintptr_t)g,
      (__attribute__((address_space(3))) uint32_t*)(uint32_t)(uintptr_t)l,
      16, 0, 0);
}

// ---------------- dt_w fp32 -> bf16 ----------------
__global__ __launch_bounds__(256) void wprep_kernel(
    const float* __restrict__ w, uint16_t* __restrict__ wb) {
  int t = blockIdx.x * 256 + threadIdx.x;  // DM*DM/4 threads
  F4 u; u.v = *(const float4*)(w + (size_t)t * 4);
  uint32_t lo = f2bf(u.f[0]) | ((uint32_t)f2bf(u.f[1]) << 16);
  uint32_t hi = f2bf(u.f[2]) | ((uint32_t)f2bf(u.f[3]) << 16);
  *(uint2*)(wb + (size_t)t * 4) = make_uint2(lo, hi);
}

// ---------------- depthwise conv k=3 pad=1 -> bf16 xf ----------------
__global__ __launch_bounds__(256) void conv_kernel(
    const float* __restrict__ x, const float* __restrict__ cw,
    const float* __restrict__ cb, uint16_t* __restrict__ xf) {
  int t = blockIdx.x * 256 + threadIdx.x;  // MROWS*DM/4 threads
  int cg = t & (DM / 4 - 1);
  int bn = t >> 8;
  int n = bn & (SEQ - 1);
  int c0 = cg * 4;
  const float* row = x + (size_t)bn * DM + c0;
  F4 xm, xc, xp;
  xm.v = make_float4(0.f, 0.f, 0.f, 0.f);
  xp.v = make_float4(0.f, 0.f, 0.f, 0.f);
  xc.v = *(const float4*)row;
  if (n > 0)       xm.v = *(const float4*)(row - DM);
  if (n < SEQ - 1) xp.v = *(const float4*)(row + DM);
  uint16_t o[4];
#pragma unroll
  for (int j = 0; j < 4; ++j) {
    int c = c0 + j;
    float v = cw[c * 3 + 0] * xm.f[j] + cw[c * 3 + 1] * xc.f[j] +
              cw[c * 3 + 2] * xp.f[j] + cb[c];
    o[j] = f2bf(v);
  }
  uint32_t lo = o[0] | ((uint32_t)o[1] << 16);
  uint32_t hi = o[2] | ((uint32_t)o[3] << 16);
  *(uint2*)(xf + (size_t)bn * DM + c0) = make_uint2(lo, hi);
}

// ---------------- dt = sigmoid(xf @ dt_w^T + dt_b)*0.099 + 0.001 ----------------
// NT GEMM, 128x128 tile, BK=64, 4 waves in 2x2, 16x16x32 bf16 MFMA.
__global__ __launch_bounds__(256) void gemm_kernel(
    const uint16_t* __restrict__ A,   // MROWS x DM bf16 (xf)
    const uint16_t* __restrict__ B,   // DM x DM bf16 (dt_w, row j, contiguous k)
    const float* __restrict__ bias,   // DM (dt_b)
    float* __restrict__ dt) {         // MROWS x DM f32
  __shared__ __align__(16) uint16_t As[128 * 64];
  __shared__ __align__(16) uint16_t Bs[128 * 64];
  const int tid = threadIdx.x;
  const int w = tid >> 6;
  const int L = tid & 63;
  const int wm = w & 1, wn = w >> 1;
  const int lane15 = L & 15, q = L >> 4;
  const int m0 = blockIdx.y * 128;
  const int n0 = blockIdx.x * 128;
  const int lr = L >> 3;        // row-in-8 for staging
  const int lc = (L & 7) * 8;   // k-col offset for staging (8 bf16 = 16B)

  f32x4 acc[4][4] = {};

  for (int kt = 0; kt < DM; kt += 64) {
#pragma unroll
    for (int r = 0; r < 4; ++r) {
      int R = (r * 4 + w) * 8;  // wave-uniform LDS base
      async_cp16(A + (size_t)(m0 + R + lr) * DM + kt + lc, &As[R * 64]);
    }
#pragma unroll
    for (int r = 0; r < 4; ++r) {
      int R = (r * 4 + w) * 8;
      async_cp16(B + (size_t)(n0 + R + lr) * DM + kt + lc, &Bs[R * 64]);
    }
    __syncthreads();  // drains vmcnt -> LDS tiles visible
#pragma unroll
    for (int ks = 0; ks < 64; ks += 32) {
      bf16x8 af[4], bfr[4];
#pragma unroll
      for (int mi = 0; mi < 4; ++mi)
        af[mi] = *(const bf16x8*)(As + (wm * 64 + mi * 16 + lane15) * 64 + ks + q * 8);
#pragma unroll
      for (int ni = 0; ni < 4; ++ni)
        bfr[ni] = *(const bf16x8*)(Bs + (wn * 64 + ni * 16 + lane15) * 64 + ks + q * 8);
#pragma unroll
      for (int mi = 0; mi < 4; ++mi)
#pragma unroll
        for (int ni = 0; ni < 4; ++ni)
          acc[mi][ni] = __builtin_amdgcn_mfma_f32_16x16x32_bf16(
              af[mi], bfr[ni], acc[mi][ni], 0, 0, 0);
    }
    __syncthreads();
  }

  // epilogue: D layout col=lane&15, row=q*4+reg
#pragma unroll
  for (int ni = 0; ni < 4; ++ni) {
    int col = n0 + wn * 64 + ni * 16 + lane15;
    float db = bias[col];
#pragma unroll
    for (int mi = 0; mi < 4; ++mi) {
      int rowb = m0 + wm * 64 + mi * 16 + q * 4;
#pragma unroll
      for (int r = 0; r < 4; ++r) {
        float z = acc[mi][ni][r] + db;
        float s = 0.099f / (1.f + __expf(-z)) + 0.001f;
        dt[(size_t)(rowb + r) * DM + col] = s;
      }
    }
  }
}

// ---------------- chunked selective scan ----------------
// lane = channel (64 consecutive channels/wave -> coalesced x/dt loads);
// D=16 states held serially in registers. 3 phases:
//  part1: local scan from 0 per chunk -> F (final state), P = exp(A*sum_dt)
//  combine: serial prefix over 32 chunks -> Sin written in-place over F
//  part3: local scan seeded with Sin, emits y

__global__ __launch_bounds__(256) void scan_part1(
    const float* __restrict__ x, const float* __restrict__ dt,
    const float* __restrict__ a_log, const float* __restrict__ bm,
    const float* __restrict__ cw, const float* __restrict__ cb,
    float* __restrict__ F, float* __restrict__ P) {
  const int c = blockIdx.x * 256 + threadIdx.x;
  const int k = blockIdx.y;
  const int b = blockIdx.z;
  const int n0 = k * CLEN;

  float A[DS], bv[DS], s[DS];
#pragma unroll
  for (int j = 0; j < 4; ++j) {
    F4 ua, ub;
    ua.v = *(const float4*)(a_log + (size_t)c * DS + j * 4);
    ub.v = *(const float4*)(bm + (size_t)c * DS + j * 4);
#pragma unroll
    for (int i = 0; i < 4; ++i) {
      A[j * 4 + i] = -log1pf(__expf(ua.f[i]));
      bv[j * 4 + i] = ub.f[i];
      s[j * 4 + i] = 0.f;
    }
  }
  const float w0 = cw[c * 3 + 0], w1 = cw[c * 3 + 1], w2 = cw[c * 3 + 2];
  const float cbv = cb[c];

  const float* xp = x + (size_t)b * SEQ * DM + c;
  const float* dp = dt + (size_t)b * SEQ * DM + c;

  float xm1 = (n0 > 0) ? xp[(size_t)(n0 - 1) * DM] : 0.f;
  float x0 = xp[(size_t)n0 * DM];
  float x1 = xp[(size_t)(n0 + 1) * DM];
  float dcur = dp[(size_t)n0 * DM];
  float sdt = 0.f;

  for (int t = 0; t < CLEN; ++t) {
    const int n = n0 + t;
    float xnext = 0.f, dnext = 0.f;
    if (n + 2 < SEQ) xnext = xp[(size_t)(n + 2) * DM];
    if (t + 1 < CLEN) dnext = dp[(size_t)(n + 1) * DM];
    float xf = w0 * xm1 + w1 * x0 + w2 * x1 + cbv;
    float u = dcur * xf;
    sdt += dcur;
#pragma unroll
    for (int d = 0; d < DS; ++d) {
      float e = __expf(dcur * A[d]);
      s[d] = e * s[d] + u * bv[d];
    }
    xm1 = x0; x0 = x1; x1 = xnext; dcur = dnext;
  }

  const size_t base = (((size_t)b * CHK + k) * DM + c) * DS;
#pragma unroll
  for (int j = 0; j < 4; ++j) {
    F4 fo, po;
#pragma unroll
    for (int i = 0; i < 4; ++i) {
      fo.f[i] = s[j * 4 + i];
      po.f[i] = __expf(A[j * 4 + i] * sdt);
    }
    *(float4*)(F + base + j * 4) = fo.v;
    *(float4*)(P + base + j * 4) = po.v;
  }
}

__global__ __launch_bounds__(256) void scan_combine(
    float* __restrict__ F, const float* __restrict__ P) {
  const int t = blockIdx.x * 256 + threadIdx.x;  // (c,d) flat
  const int b = blockIdx.y;
  const size_t stride = (size_t)DM * DS;
  const size_t base = (size_t)b * CHK * stride + t;
  float carry = 0.f;
#pragma unroll
  for (int k = 0; k < CHK; ++k) {
    const size_t idx = base + (size_t)k * stride;
    float f = F[idx], p = P[idx];
    F[idx] = carry;               // Sin for chunk k
    carry = p * carry + f;
  }
}

__global__ __launch_bounds__(256) void scan_part3(
    const float* __restrict__ x, const float* __restrict__ dt,
    const float* __restrict__ a_log, const float* __restrict__ bm,
    const float* __restrict__ cm, const float* __restrict__ cw,
    const float* __restrict__ cb, const float* __restrict__ Sin,
    float* __restrict__ out) {
  const int c = blockIdx.x * 256 + threadIdx.x;
  const int k = blockIdx.y;
  const int b = blockIdx.z;
  const int n0 = k * CLEN;

  float A[DS], bv[DS], cv[DS], s[DS];
  const size_t base = (((size_t)b * CHK + k) * DM + c) * DS;
#pragma unroll
  for (int j = 0; j < 4; ++j) {
    F4 ua, ub, uc, us;
    ua.v = *(const float4*)(a_log + (size_t)c * DS + j * 4);
    ub.v = *(const float4*)(bm + (size_t)c * DS + j * 4);
    uc.v = *(const float4*)(cm + (size_t)c * DS + j * 4);
    us.v = *(const float4*)(Sin + base + j * 4);
#pragma unroll
    for (int i = 0; i < 4; ++i) {
      A[j * 4 + i] = -log1pf(__expf(ua.f[i]));
      bv[j * 4 + i] = ub.f[i];
      cv[j * 4 + i] = uc.f[i];
      s[j * 4 + i] = us.f[i];
    }
  }
  const float w0 = cw[c * 3 + 0], w1 = cw[c * 3 + 1], w2 = cw[c * 3 + 2];
  const float cbv = cb[c];

  const float* xp = x + (size_t)b * SEQ * DM + c;
  const float* dp = dt + (size_t)b * SEQ * DM + c;
  float* op = out + (size_t)b * SEQ * DM + c;

  float xm1 = (n0 > 0) ? xp[(size_t)(n0 - 1) * DM] : 0.f;
  float x0 = xp[(size_t)n0 * DM];
  float x1 = xp[(size_t)(n0 + 1) * DM];
  float dcur = dp[(size_t)n0 * DM];

  for (int t = 0; t < CLEN; ++t) {
    const int n = n0 + t;
    float xnext = 0.f, dnext = 0.f;
    if (n + 2 < SEQ) xnext = xp[(size_t)(n + 2) * DM];
    if (t + 1 < CLEN) dnext = dp[(size_t)(n + 1) * DM];
    float xf = w0 * xm1 + w1 * x0 + w2 * x1 + cbv;
    float u = dcur * xf;
    float y0 = 0.f, y1 = 0.f;
#pragma unroll
    for (int d = 0; d < DS; d += 2) {
      float e0 = __expf(dcur * A[d]);
      float e1 = __expf(dcur * A[d + 1]);
      s[d] = e0 * s[d] + u * bv[d];
      s[d + 1] = e1 * s[d + 1] + u * bv[d + 1];
      y0 += cv[d] * s[d];
      y1 += cv[d + 1] * s[d + 1];
    }
    op[(size_t)n * DM] = y0 + y1;
    xm1 = x0; x0 = x1; x1 = xnext; dcur = dnext;
  }
}

extern "C" void kernel_launch(void* const* d_in, const int* in_sizes, int n_in,
                              void* d_out, int out_size, void* d_ws, size_t ws_size,
                              hipStream_t stream) {
  const float* x     = (const float*)d_in[0];
  const float* a_log = (const float*)d_in[1];
  const float* bm    = (const float*)d_in[2];
  const float* cm    = (const float*)d_in[3];
  const float* dt_w  = (const float*)d_in[4];
  const float* dt_b  = (const float*)d_in[5];
  const float* cw    = (const float*)d_in[6];
  const float* cb    = (const float*)d_in[7];
  float* out = (float*)d_out;

  char* ws = (char*)d_ws;
  uint16_t* xf_bf = (uint16_t*)ws;                                       // 32 MB
  uint16_t* w_bf  = (uint16_t*)(ws + (size_t)MROWS * DM * 2);            // 2 MB
  float* dt = (float*)(ws + (size_t)MROWS * DM * 2 + (size_t)DM * DM * 2);  // 64 MB
  float* Fbuf = dt + (size_t)MROWS * DM;                                 // 16.8 MB
  float* Pbuf = Fbuf + (size_t)BSZ * CHK * DM * DS;                      // 16.8 MB

  hipLaunchKernelGGL(wprep_kernel, dim3(DM * DM / 1024), dim3(256), 0, stream,
                     dt_w, w_bf);
  hipLaunchKernelGGL(conv_kernel, dim3(MROWS * DM / 1024), dim3(256), 0, stream,
                     x, cw, cb, xf_bf);
  hipLaunchKernelGGL(gemm_kernel, dim3(DM / 128, MROWS / 128), dim3(256), 0,
                     stream, xf_bf, w_bf, dt_b, dt);
  hipLaunchKernelGGL(scan_part1, dim3(DM / 256, CHK, BSZ), dim3(256), 0, stream,
                     x, dt, a_log, bm, cw, cb, Fbuf, Pbuf);
  hipLaunchKernelGGL(scan_combine, dim3(DM * DS / 256, BSZ), dim3(256), 0,
                     stream, Fbuf, Pbuf);
  hipLaunchKernelGGL(scan_part3, dim3(DM / 256, CHK, BSZ), dim3(256), 0, stream,
                     x, dt, a_log, bm, cm, cw, cb, Fbuf, out);
}

// Round 3
// 310.026 us; speedup vs baseline: 3.4126x; 1.1332x over previous
//
#include <hip/hip_runtime.h>
#include <stdint.h>

#define BSZ 8
#define SEQ 2048
#define DM 1024
#define DS 16
#define MROWS (BSZ * SEQ)  // 16384
#define CHK 64             // chunks over SEQ
#define CLEN (SEQ / CHK)   // 32 steps per chunk
#define LOG2E 1.4426950408889634f

typedef __bf16 bf16x8 __attribute__((ext_vector_type(8)));
typedef float f32x4 __attribute__((ext_vector_type(4)));

union F4 { float4 v; float f[4]; };

// round-to-nearest-even fp32 -> bf16 (bit pattern)
__device__ __forceinline__ uint16_t f2bf(float f) {
  uint32_t u = __float_as_uint(f);
  u += 0x7FFFu + ((u >> 16) & 1u);
  return (uint16_t)(u >> 16);
}

// async global->LDS, 16B per lane; LDS base must be wave-uniform.
__device__ __forceinline__ void async_cp16(const void* g, void* l) {
  __builtin_amdgcn_global_load_lds(
      (const __attribute__((address_space(1))) uint32_t*)(uintptr_t)g,
      (__attribute__((address_space(3))) uint32_t*)(uint32_t)(uintptr_t)l,
      16, 0, 0);
}

// ---------------- dt_w fp32 -> bf16 ----------------
__global__ __launch_bounds__(256) void wprep_kernel(
    const float* __restrict__ w, uint16_t* __restrict__ wb) {
  int t = blockIdx.x * 256 + threadIdx.x;  // DM*DM/4 threads
  F4 u; u.v = *(const float4*)(w + (size_t)t * 4);
  uint32_t lo = f2bf(u.f[0]) | ((uint32_t)f2bf(u.f[1]) << 16);
  uint32_t hi = f2bf(u.f[2]) | ((uint32_t)f2bf(u.f[3]) << 16);
  *(uint2*)(wb + (size_t)t * 4) = make_uint2(lo, hi);
}

// ---------------- scan parameter prep ----------------
// A2c[c*16+d]   = -softplus(a_log)*log2e         (for part1/part3, c-major)
// A2t[t]        = same, d-plane-major (combine layout)
// cb2[c*16+d]   = b*c  (scaled-state output weights)
__global__ __launch_bounds__(256) void aprep_kernel(
    const float* __restrict__ a_log, const float* __restrict__ bm,
    const float* __restrict__ cm, float* __restrict__ A2c,
    float* __restrict__ A2t, float* __restrict__ cb2) {
  int e = blockIdx.x * 256 + threadIdx.x;  // DM*DS threads
  float a = a_log[e];
  float A2 = -log1pf(__expf(a)) * LOG2E;
  A2c[e] = A2;
  cb2[e] = bm[e] * cm[e];
  int c = e >> 4, d = e & 15;
  int j = d >> 2, i = d & 3;
  A2t[((size_t)j * DM + c) * 4 + i] = A2;
}

// ---------------- depthwise conv k=3 pad=1 -> bf16 xf ----------------
__global__ __launch_bounds__(256) void conv_kernel(
    const float* __restrict__ x, const float* __restrict__ cw,
    const float* __restrict__ cb, uint16_t* __restrict__ xf) {
  int t = blockIdx.x * 256 + threadIdx.x;  // MROWS*DM/4 threads
  int cg = t & (DM / 4 - 1);
  int bn = t >> 8;
  int n = bn & (SEQ - 1);
  int c0 = cg * 4;
  const float* row = x + (size_t)bn * DM + c0;
  F4 xm, xc, xp;
  xm.v = make_float4(0.f, 0.f, 0.f, 0.f);
  xp.v = make_float4(0.f, 0.f, 0.f, 0.f);
  xc.v = *(const float4*)row;
  if (n > 0)       xm.v = *(const float4*)(row - DM);
  if (n < SEQ - 1) xp.v = *(const float4*)(row + DM);
  uint16_t o[4];
#pragma unroll
  for (int j = 0; j < 4; ++j) {
    int c = c0 + j;
    float v = cw[c * 3 + 0] * xm.f[j] + cw[c * 3 + 1] * xc.f[j] +
              cw[c * 3 + 2] * xp.f[j] + cb[c];
    o[j] = f2bf(v);
  }
  uint32_t lo = o[0] | ((uint32_t)o[1] << 16);
  uint32_t hi = o[2] | ((uint32_t)o[3] << 16);
  *(uint2*)(xf + (size_t)bn * DM + c0) = make_uint2(lo, hi);
}

// ---------------- dt = sigmoid(xf @ dt_w^T + dt_b)*0.099 + 0.001 ----------------
// NT GEMM, 128x128 tile, BK=64, 4 waves in 2x2, 16x16x32 bf16 MFMA.
__global__ __launch_bounds__(256) void gemm_kernel(
    const uint16_t* __restrict__ A,   // MROWS x DM bf16 (xf)
    const uint16_t* __restrict__ B,   // DM x DM bf16 (dt_w, row j, contiguous k)
    const float* __restrict__ bias,   // DM (dt_b)
    float* __restrict__ dt) {         // MROWS x DM f32
  __shared__ __align__(16) uint16_t As[128 * 64];
  __shared__ __align__(16) uint16_t Bs[128 * 64];
  const int tid = threadIdx.x;
  const int w = tid >> 6;
  const int L = tid & 63;
  const int wm = w & 1, wn = w >> 1;
  const int lane15 = L & 15, q = L >> 4;
  const int m0 = blockIdx.y * 128;
  const int n0 = blockIdx.x * 128;
  const int lr = L >> 3;        // row-in-8 for staging
  const int lc = (L & 7) * 8;   // k-col offset for staging (8 bf16 = 16B)

  f32x4 acc[4][4] = {};

  for (int kt = 0; kt < DM; kt += 64) {
#pragma unroll
    for (int r = 0; r < 4; ++r) {
      int R = (r * 4 + w) * 8;  // wave-uniform LDS base
      async_cp16(A + (size_t)(m0 + R + lr) * DM + kt + lc, &As[R * 64]);
    }
#pragma unroll
    for (int r = 0; r < 4; ++r) {
      int R = (r * 4 + w) * 8;
      async_cp16(B + (size_t)(n0 + R + lr) * DM + kt + lc, &Bs[R * 64]);
    }
    __syncthreads();  // drains vmcnt -> LDS tiles visible
#pragma unroll
    for (int ks = 0; ks < 64; ks += 32) {
      bf16x8 af[4], bfr[4];
#pragma unroll
      for (int mi = 0; mi < 4; ++mi)
        af[mi] = *(const bf16x8*)(As + (wm * 64 + mi * 16 + lane15) * 64 + ks + q * 8);
#pragma unroll
      for (int ni = 0; ni < 4; ++ni)
        bfr[ni] = *(const bf16x8*)(Bs + (wn * 64 + ni * 16 + lane15) * 64 + ks + q * 8);
#pragma unroll
      for (int mi = 0; mi < 4; ++mi)
#pragma unroll
        for (int ni = 0; ni < 4; ++ni)
          acc[mi][ni] = __builtin_amdgcn_mfma_f32_16x16x32_bf16(
              af[mi], bfr[ni], acc[mi][ni], 0, 0, 0);
    }
    __syncthreads();
  }

  // epilogue: D layout col=lane&15, row=q*4+reg
#pragma unroll
  for (int ni = 0; ni < 4; ++ni) {
    int col = n0 + wn * 64 + ni * 16 + lane15;
    float db = bias[col];
#pragma unroll
    for (int mi = 0; mi < 4; ++mi) {
      int rowb = m0 + wm * 64 + mi * 16 + q * 4;
#pragma unroll
      for (int r = 0; r < 4; ++r) {
        float z = acc[mi][ni][r] + db;
        float s = 0.099f / (1.f + __expf(-z)) + 0.001f;
        dt[(size_t)(rowb + r) * DM + col] = s;
      }
    }
  }
}

// ---------------- chunked selective scan (scaled state s~ = s/b) ----------------
// lane = channel; D=16 states in registers. Recurrence: s~ = e*s~ + u,
// y = sum_d (c*b)_d * s~_d. F layout is d-plane-major for coalescing:
// F[(((b*CHK+k)*4 + j)*DM + c)*4 + i], d = j*4+i.

__global__ __launch_bounds__(256) void scan_part1(
    const float* __restrict__ x, const float* __restrict__ dt,
    const float* __restrict__ A2c, const float* __restrict__ cw,
    const float* __restrict__ cb, float* __restrict__ F,
    float* __restrict__ Sdt) {
  const int c = blockIdx.x * 256 + threadIdx.x;
  const int k = blockIdx.y;
  const int b = blockIdx.z;
  const int n0 = k * CLEN;

  float A2[DS], s[DS];
#pragma unroll
  for (int j = 0; j < 4; ++j) {
    F4 ua; ua.v = *(const float4*)(A2c + (size_t)c * DS + j * 4);
#pragma unroll
    for (int i = 0; i < 4; ++i) {
      A2[j * 4 + i] = ua.f[i];
      s[j * 4 + i] = 0.f;
    }
  }
  const float w0 = cw[c * 3 + 0], w1 = cw[c * 3 + 1], w2 = cw[c * 3 + 2];
  const float cbv = cb[c];

  const float* xp = x + (size_t)b * SEQ * DM + c;
  const float* dp = dt + (size_t)b * SEQ * DM + c;

  float xm1 = (n0 > 0) ? xp[(size_t)(n0 - 1) * DM] : 0.f;
  float x0 = xp[(size_t)n0 * DM];
  float x1 = xp[(size_t)(n0 + 1) * DM];
  float dcur = dp[(size_t)n0 * DM];
  float sdt = 0.f;

  for (int t = 0; t < CLEN; ++t) {
    const int n = n0 + t;
    float xnext = 0.f, dnext = 0.f;
    if (n + 2 < SEQ) xnext = xp[(size_t)(n + 2) * DM];
    if (t + 1 < CLEN) dnext = dp[(size_t)(n + 1) * DM];
    float xf = w0 * xm1 + w1 * x0 + w2 * x1 + cbv;
    float u = dcur * xf;
    sdt += dcur;
#pragma unroll
    for (int d = 0; d < DS; ++d) {
      float e = __builtin_amdgcn_exp2f(dcur * A2[d]);
      s[d] = fmaf(e, s[d], u);
    }
    xm1 = x0; x0 = x1; x1 = xnext; dcur = dnext;
  }

  const size_t kk = (size_t)b * CHK + k;
#pragma unroll
  for (int j = 0; j < 4; ++j) {
    F4 fo;
#pragma unroll
    for (int i = 0; i < 4; ++i) fo.f[i] = s[j * 4 + i];
    *(float4*)(F + ((kk * 4 + j) * DM + c) * 4) = fo.v;
  }
  Sdt[kk * DM + c] = sdt;
}

// serial prefix over CHK chunks per (b,c,d); F overwritten with carry-in (Sin).
__global__ __launch_bounds__(256) void scan_combine(
    float* __restrict__ F, const float* __restrict__ Sdt,
    const float* __restrict__ A2t) {
  const int t = blockIdx.x * 256 + threadIdx.x;  // flat (j,c,i)
  const int b = blockIdx.y;
  const int c = (t >> 2) & (DM - 1);
  const float A2 = A2t[t];
  const size_t stride = (size_t)DM * DS;
  const size_t base = (size_t)b * CHK * stride + t;
  const size_t sbase = (size_t)b * CHK * DM + c;
  float carry = 0.f;
#pragma unroll 4
  for (int k = 0; k < CHK; ++k) {
    const size_t idx = base + (size_t)k * stride;
    float f = F[idx];
    float p = __builtin_amdgcn_exp2f(A2 * Sdt[sbase + (size_t)k * DM]);
    F[idx] = carry;               // Sin for chunk k
    carry = fmaf(p, carry, f);
  }
}

__global__ __launch_bounds__(256) void scan_part3(
    const float* __restrict__ x, const float* __restrict__ dt,
    const float* __restrict__ A2c, const float* __restrict__ cb2m,
    const float* __restrict__ cw, const float* __restrict__ cb,
    const float* __restrict__ Sin, float* __restrict__ out) {
  const int c = blockIdx.x * 256 + threadIdx.x;
  const int k = blockIdx.y;
  const int b = blockIdx.z;
  const int n0 = k * CLEN;

  float A2[DS], cb2[DS], s[DS];
  const size_t kk = (size_t)b * CHK + k;
#pragma unroll
  for (int j = 0; j < 4; ++j) {
    F4 ua, uc, us;
    ua.v = *(const float4*)(A2c + (size_t)c * DS + j * 4);
    uc.v = *(const float4*)(cb2m + (size_t)c * DS + j * 4);
    us.v = *(const float4*)(Sin + ((kk * 4 + j) * DM + c) * 4);
#pragma unroll
    for (int i = 0; i < 4; ++i) {
      A2[j * 4 + i] = ua.f[i];
      cb2[j * 4 + i] = uc.f[i];
      s[j * 4 + i] = us.f[i];
    }
  }
  const float w0 = cw[c * 3 + 0], w1 = cw[c * 3 + 1], w2 = cw[c * 3 + 2];
  const float cbv = cb[c];

  const float* xp = x + (size_t)b * SEQ * DM + c;
  const float* dp = dt + (size_t)b * SEQ * DM + c;
  float* op = out + (size_t)b * SEQ * DM + c;

  float xm1 = (n0 > 0) ? xp[(size_t)(n0 - 1) * DM] : 0.f;
  float x0 = xp[(size_t)n0 * DM];
  float x1 = xp[(size_t)(n0 + 1) * DM];
  float dcur = dp[(size_t)n0 * DM];

  for (int t = 0; t < CLEN; ++t) {
    const int n = n0 + t;
    float xnext = 0.f, dnext = 0.f;
    if (n + 2 < SEQ) xnext = xp[(size_t)(n + 2) * DM];
    if (t + 1 < CLEN) dnext = dp[(size_t)(n + 1) * DM];
    float xf = w0 * xm1 + w1 * x0 + w2 * x1 + cbv;
    float u = dcur * xf;
    float y0 = 0.f, y1 = 0.f;
#pragma unroll
    for (int d = 0; d < DS; d += 2) {
      float e0 = __builtin_amdgcn_exp2f(dcur * A2[d]);
      float e1 = __builtin_amdgcn_exp2f(dcur * A2[d + 1]);
      s[d] = fmaf(e0, s[d], u);
      s[d + 1] = fmaf(e1, s[d + 1], u);
      y0 = fmaf(cb2[d], s[d], y0);
      y1 = fmaf(cb2[d + 1], s[d + 1], y1);
    }
    op[(size_t)n * DM] = y0 + y1;
    xm1 = x0; x0 = x1; x1 = xnext; dcur = dnext;
  }
}

extern "C" void kernel_launch(void* const* d_in, const int* in_sizes, int n_in,
                              void* d_out, int out_size, void* d_ws, size_t ws_size,
                              hipStream_t stream) {
  const float* x     = (const float*)d_in[0];
  const float* a_log = (const float*)d_in[1];
  const float* bm    = (const float*)d_in[2];
  const float* cm    = (const float*)d_in[3];
  const float* dt_w  = (const float*)d_in[4];
  const float* dt_b  = (const float*)d_in[5];
  const float* cw    = (const float*)d_in[6];
  const float* cb    = (const float*)d_in[7];
  float* out = (float*)d_out;

  char* ws = (char*)d_ws;
  uint16_t* xf_bf = (uint16_t*)ws;                                          // 32 MB
  uint16_t* w_bf  = (uint16_t*)(ws + (size_t)MROWS * DM * 2);               // 2 MB
  float* dt   = (float*)(ws + (size_t)MROWS * DM * 2 + (size_t)DM * DM * 2);  // 64 MB
  float* Fbuf = dt + (size_t)MROWS * DM;                                    // 33.5 MB
  float* Sdt  = Fbuf + (size_t)BSZ * CHK * DM * DS;                         // 2 MB
  float* A2c  = Sdt + (size_t)BSZ * CHK * DM;                               // 64 KB
  float* A2t  = A2c + (size_t)DM * DS;                                      // 64 KB
  float* cb2  = A2t + (size_t)DM * DS;                                      // 64 KB

  hipLaunchKernelGGL(wprep_kernel, dim3(DM * DM / 1024), dim3(256), 0, stream,
                     dt_w, w_bf);
  hipLaunchKernelGGL(aprep_kernel, dim3(DM * DS / 256), dim3(256), 0, stream,
                     a_log, bm, cm, A2c, A2t, cb2);
  hipLaunchKernelGGL(conv_kernel, dim3(MROWS * DM / 1024), dim3(256), 0, stream,
                     x, cw, cb, xf_bf);
  hipLaunchKernelGGL(gemm_kernel, dim3(DM / 128, MROWS / 128), dim3(256), 0,
                     stream, xf_bf, w_bf, dt_b, dt);
  hipLaunchKernelGGL(scan_part1, dim3(DM / 256, CHK, BSZ), dim3(256), 0, stream,
                     x, dt, A2c, cw, cb, Fbuf, Sdt);
  hipLaunchKernelGGL(scan_combine, dim3(DM * DS / 256, BSZ), dim3(256), 0,
                     stream, Fbuf, Sdt, A2t);
  hipLaunchKernelGGL(scan_part3, dim3(DM / 256, CHK, BSZ), dim3(256), 0, stream,
                     x, dt, A2c, cb2, cw, cb, Fbuf, out);
}

// Round 4
// 297.382 us; speedup vs baseline: 3.5577x; 1.0425x over previous
//
#include <hip/hip_runtime.h>
#include <stdint.h>

#define BSZ 8
#define SEQ 2048
#define DM 1024
#define DS 16
#define MROWS (BSZ * SEQ)  // 16384
#define CHK 64             // chunks over SEQ
#define CLEN (SEQ / CHK)   // 32 steps per chunk
#define LOG2E 1.4426950408889634f

typedef __bf16 bf16x8 __attribute__((ext_vector_type(8)));
typedef float f32x4 __attribute__((ext_vector_type(4)));

union F4 { float4 v; float f[4]; };

// round-to-nearest-even fp32 -> bf16 (bit pattern)
__device__ __forceinline__ uint16_t f2bf(float f) {
  uint32_t u = __float_as_uint(f);
  u += 0x7FFFu + ((u >> 16) & 1u);
  return (uint16_t)(u >> 16);
}

// pack two floats as f16 pair in a uint32 (a = lo, b = hi)
__device__ __forceinline__ uint32_t pack_h2(float a, float b) {
  _Float16 ha = (_Float16)a, hb = (_Float16)b;
  uint16_t ua = __builtin_bit_cast(uint16_t, ha);
  uint16_t ub = __builtin_bit_cast(uint16_t, hb);
  return (uint32_t)ua | ((uint32_t)ub << 16);
}
__device__ __forceinline__ float unpack_lo(uint32_t v) {
  return (float)__builtin_bit_cast(_Float16, (uint16_t)(v & 0xffffu));
}
__device__ __forceinline__ float unpack_hi(uint32_t v) {
  return (float)__builtin_bit_cast(_Float16, (uint16_t)(v >> 16));
}

// async global->LDS, 16B per lane; LDS base must be wave-uniform.
__device__ __forceinline__ void async_cp16(const void* g, void* l) {
  __builtin_amdgcn_global_load_lds(
      (const __attribute__((address_space(1))) uint32_t*)(uintptr_t)g,
      (__attribute__((address_space(3))) uint32_t*)(uint32_t)(uintptr_t)l,
      16, 0, 0);
}

// ---------------- dt_w fp32 -> bf16 ----------------
__global__ __launch_bounds__(256) void wprep_kernel(
    const float* __restrict__ w, uint16_t* __restrict__ wb) {
  int t = blockIdx.x * 256 + threadIdx.x;  // DM*DM/4 threads
  F4 u; u.v = *(const float4*)(w + (size_t)t * 4);
  uint32_t lo = f2bf(u.f[0]) | ((uint32_t)f2bf(u.f[1]) << 16);
  uint32_t hi = f2bf(u.f[2]) | ((uint32_t)f2bf(u.f[3]) << 16);
  *(uint2*)(wb + (size_t)t * 4) = make_uint2(lo, hi);
}

// ---------------- scan parameter prep ----------------
__global__ __launch_bounds__(256) void aprep_kernel(
    const float* __restrict__ a_log, const float* __restrict__ bm,
    const float* __restrict__ cm, float* __restrict__ A2c,
    float* __restrict__ A2t, float* __restrict__ cb2) {
  int e = blockIdx.x * 256 + threadIdx.x;  // DM*DS threads
  float a = a_log[e];
  float A2 = -log1pf(__expf(a)) * LOG2E;
  A2c[e] = A2;
  cb2[e] = bm[e] * cm[e];
  int c = e >> 4, d = e & 15;
  int j = d >> 2, i = d & 3;
  A2t[((size_t)j * DM + c) * 4 + i] = A2;
}

// ---------------- depthwise conv k=3 pad=1 -> bf16 xf ----------------
__global__ __launch_bounds__(256) void conv_kernel(
    const float* __restrict__ x, const float* __restrict__ cw,
    const float* __restrict__ cb, uint16_t* __restrict__ xf) {
  int t = blockIdx.x * 256 + threadIdx.x;  // MROWS*DM/4 threads
  int cg = t & (DM / 4 - 1);
  int bn = t >> 8;
  int n = bn & (SEQ - 1);
  int c0 = cg * 4;
  const float* row = x + (size_t)bn * DM + c0;
  F4 xm, xc, xp;
  xm.v = make_float4(0.f, 0.f, 0.f, 0.f);
  xp.v = make_float4(0.f, 0.f, 0.f, 0.f);
  xc.v = *(const float4*)row;
  if (n > 0)       xm.v = *(const float4*)(row - DM);
  if (n < SEQ - 1) xp.v = *(const float4*)(row + DM);
  uint16_t o[4];
#pragma unroll
  for (int j = 0; j < 4; ++j) {
    int c = c0 + j;
    float v = cw[c * 3 + 0] * xm.f[j] + cw[c * 3 + 1] * xc.f[j] +
              cw[c * 3 + 2] * xp.f[j] + cb[c];
    o[j] = f2bf(v);
  }
  uint32_t lo = o[0] | ((uint32_t)o[1] << 16);
  uint32_t hi = o[2] | ((uint32_t)o[3] << 16);
  *(uint2*)(xf + (size_t)bn * DM + c0) = make_uint2(lo, hi);
}

// ---------------- dt GEMM + fused epilogue -> packed (u, dt) f16x2 ----------------
// NT GEMM, 128x128 tile, BK=64, 4 waves 2x2, 16x16x32 bf16 MFMA.
// LDS k-chunk XOR swizzle: slot j of row r holds source chunk j^(r&7)
// (kills the 16-way bank conflict of the 128B row stride; staging source
// is lane-permuted within each 128B row so global_load_lds stays legal).
__global__ __launch_bounds__(256) void gemm_kernel(
    const uint16_t* __restrict__ A,   // MROWS x DM bf16 (xf)
    const uint16_t* __restrict__ B,   // DM x DM bf16 (dt_w)
    const float* __restrict__ bias,   // DM (dt_b)
    uint32_t* __restrict__ ud) {      // MROWS x DM packed f16x2 (u, dt)
  __shared__ __align__(16) uint16_t As[128 * 64];
  __shared__ __align__(16) uint16_t Bs[128 * 64];
  const int tid = threadIdx.x;
  const int w = tid >> 6;
  const int L = tid & 63;
  const int wm = w & 1, wn = w >> 1;
  const int lane15 = L & 15, q = L >> 4;
  const int m0 = blockIdx.y * 128;
  const int n0 = blockIdx.x * 128;
  const int lr = L >> 3;                  // row-in-8 for staging
  const int lc = (((L & 7) ^ lr)) * 8;    // swizzled source k-chunk (8 bf16 = 16B)
  const int r7 = lane15 & 7;              // reader row&7

  f32x4 acc[4][4] = {};

  for (int kt = 0; kt < DM; kt += 64) {
#pragma unroll
    for (int r = 0; r < 4; ++r) {
      int R = (r * 4 + w) * 8;  // wave-uniform LDS base
      async_cp16(A + (size_t)(m0 + R + lr) * DM + kt + lc, &As[R * 64]);
    }
#pragma unroll
    for (int r = 0; r < 4; ++r) {
      int R = (r * 4 + w) * 8;
      async_cp16(B + (size_t)(n0 + R + lr) * DM + kt + lc, &Bs[R * 64]);
    }
    __syncthreads();  // drains vmcnt -> LDS tiles visible
#pragma unroll
    for (int ks = 0; ks < 64; ks += 32) {
      bf16x8 af[4], bfr[4];
      const int jbase = ks >> 3;
#pragma unroll
      for (int mi = 0; mi < 4; ++mi)
        af[mi] = *(const bf16x8*)(As + (wm * 64 + mi * 16 + lane15) * 64 +
                                  (((jbase + q) ^ r7) << 3));
#pragma unroll
      for (int ni = 0; ni < 4; ++ni)
        bfr[ni] = *(const bf16x8*)(Bs + (wn * 64 + ni * 16 + lane15) * 64 +
                                   (((jbase + q) ^ r7) << 3));
#pragma unroll
      for (int mi = 0; mi < 4; ++mi)
#pragma unroll
        for (int ni = 0; ni < 4; ++ni)
          acc[mi][ni] = __builtin_amdgcn_mfma_f32_16x16x32_bf16(
              af[mi], bfr[ni], acc[mi][ni], 0, 0, 0);
    }
    __syncthreads();
  }

  // epilogue: D layout col=lane&15, row=q*4+reg. Fuse sigmoid + u=dt*xf,
  // write packed (u, dt) f16x2. xf rows are L2-hot (same rows as A-tile).
#pragma unroll
  for (int ni = 0; ni < 4; ++ni) {
    int col = n0 + wn * 64 + ni * 16 + lane15;
    float db = bias[col];
#pragma unroll
    for (int mi = 0; mi < 4; ++mi) {
      int rowb = m0 + wm * 64 + mi * 16 + q * 4;
#pragma unroll
      for (int r = 0; r < 4; ++r) {
        size_t idx = (size_t)(rowb + r) * DM + col;
        float z = acc[mi][ni][r] + db;
        float dtv = 0.099f / (1.f + __expf(-z)) + 0.001f;
        float xfv = __uint_as_float((uint32_t)A[idx] << 16);
        ud[idx] = pack_h2(dtv * xfv, dtv);
      }
    }
  }
}

// ---------------- chunked selective scan (scaled state s~) ----------------
// lane = channel; one packed uint32 (u, dt) load per step.
// F layout d-plane-major: F[(((b*CHK+k)*4 + j)*DM + c)*4 + i], d = j*4+i.

__global__ __launch_bounds__(256) void scan_part1(
    const uint32_t* __restrict__ ud, const float* __restrict__ A2c,
    float* __restrict__ F, float* __restrict__ Sdt) {
  const int c = blockIdx.x * 256 + threadIdx.x;
  const int k = blockIdx.y;
  const int b = blockIdx.z;
  const int n0 = k * CLEN;

  float A2[DS], s[DS];
#pragma unroll
  for (int j = 0; j < 4; ++j) {
    F4 ua; ua.v = *(const float4*)(A2c + (size_t)c * DS + j * 4);
#pragma unroll
    for (int i = 0; i < 4; ++i) {
      A2[j * 4 + i] = ua.f[i];
      s[j * 4 + i] = 0.f;
    }
  }

  const uint32_t* up = ud + ((size_t)b * SEQ + n0) * DM + c;
  uint32_t c0 = up[0];
  uint32_t c1 = up[DM];
  float sdt = 0.f;

  for (int t = 0; t < CLEN; ++t) {
    uint32_t c2 = 0;
    if (t + 2 < CLEN) c2 = up[(size_t)(t + 2) * DM];
    float uv = unpack_lo(c0);
    float dtv = unpack_hi(c0);
    sdt += dtv;
#pragma unroll
    for (int d = 0; d < DS; ++d) {
      float e = __builtin_amdgcn_exp2f(dtv * A2[d]);
      s[d] = fmaf(e, s[d], uv);
    }
    c0 = c1; c1 = c2;
  }

  const size_t kk = (size_t)b * CHK + k;
#pragma unroll
  for (int j = 0; j < 4; ++j) {
    F4 fo;
#pragma unroll
    for (int i = 0; i < 4; ++i) fo.f[i] = s[j * 4 + i];
    *(float4*)(F + ((kk * 4 + j) * DM + c) * 4) = fo.v;
  }
  Sdt[kk * DM + c] = sdt;
}

// serial prefix over CHK chunks per (b,c,d); F overwritten with carry-in (Sin).
__global__ __launch_bounds__(256) void scan_combine(
    float* __restrict__ F, const float* __restrict__ Sdt,
    const float* __restrict__ A2t) {
  const int t = blockIdx.x * 256 + threadIdx.x;  // flat (j,c,i)
  const int b = blockIdx.y;
  const int c = (t >> 2) & (DM - 1);
  const float A2 = A2t[t];
  const size_t stride = (size_t)DM * DS;
  const size_t base = (size_t)b * CHK * stride + t;
  const size_t sbase = (size_t)b * CHK * DM + c;
  float carry = 0.f;
#pragma unroll 4
  for (int k = 0; k < CHK; ++k) {
    const size_t idx = base + (size_t)k * stride;
    float f = F[idx];
    float p = __builtin_amdgcn_exp2f(A2 * Sdt[sbase + (size_t)k * DM]);
    F[idx] = carry;               // Sin for chunk k
    carry = fmaf(p, carry, f);
  }
}

__global__ __launch_bounds__(256) void scan_part3(
    const uint32_t* __restrict__ ud, const float* __restrict__ A2c,
    const float* __restrict__ cb2m, const float* __restrict__ Sin,
    float* __restrict__ out) {
  const int c = blockIdx.x * 256 + threadIdx.x;
  const int k = blockIdx.y;
  const int b = blockIdx.z;
  const int n0 = k * CLEN;

  float A2[DS], cb2[DS], s[DS];
  const size_t kk = (size_t)b * CHK + k;
#pragma unroll
  for (int j = 0; j < 4; ++j) {
    F4 ua, uc, us;
    ua.v = *(const float4*)(A2c + (size_t)c * DS + j * 4);
    uc.v = *(const float4*)(cb2m + (size_t)c * DS + j * 4);
    us.v = *(const float4*)(Sin + ((kk * 4 + j) * DM + c) * 4);
#pragma unroll
    for (int i = 0; i < 4; ++i) {
      A2[j * 4 + i] = ua.f[i];
      cb2[j * 4 + i] = uc.f[i];
      s[j * 4 + i] = us.f[i];
    }
  }

  const uint32_t* up = ud + ((size_t)b * SEQ + n0) * DM + c;
  float* op = out + ((size_t)b * SEQ + n0) * DM + c;
  uint32_t c0 = up[0];
  uint32_t c1 = up[DM];

  for (int t = 0; t < CLEN; ++t) {
    uint32_t c2 = 0;
    if (t + 2 < CLEN) c2 = up[(size_t)(t + 2) * DM];
    float uv = unpack_lo(c0);
    float dtv = unpack_hi(c0);
    float y0 = 0.f, y1 = 0.f;
#pragma unroll
    for (int d = 0; d < DS; d += 2) {
      float e0 = __builtin_amdgcn_exp2f(dtv * A2[d]);
      float e1 = __builtin_amdgcn_exp2f(dtv * A2[d + 1]);
      s[d] = fmaf(e0, s[d], uv);
      s[d + 1] = fmaf(e1, s[d + 1], uv);
      y0 = fmaf(cb2[d], s[d], y0);
      y1 = fmaf(cb2[d + 1], s[d + 1], y1);
    }
    op[(size_t)t * DM] = y0 + y1;
    c0 = c1; c1 = c2;
  }
}

extern "C" void kernel_launch(void* const* d_in, const int* in_sizes, int n_in,
                              void* d_out, int out_size, void* d_ws, size_t ws_size,
                              hipStream_t stream) {
  const float* x     = (const float*)d_in[0];
  const float* a_log = (const float*)d_in[1];
  const float* bm    = (const float*)d_in[2];
  const float* cm    = (const float*)d_in[3];
  const float* dt_w  = (const float*)d_in[4];
  const float* dt_b  = (const float*)d_in[5];
  const float* cw    = (const float*)d_in[6];
  const float* cb    = (const float*)d_in[7];
  float* out = (float*)d_out;

  char* ws = (char*)d_ws;
  uint16_t* xf_bf = (uint16_t*)ws;                                   // 32 MB
  uint16_t* w_bf  = (uint16_t*)(ws + (size_t)MROWS * DM * 2);        // 2 MB
  uint32_t* ud = (uint32_t*)(ws + (size_t)MROWS * DM * 2 + (size_t)DM * DM * 2);  // 64 MB
  float* Fbuf = (float*)(ud + (size_t)MROWS * DM);                   // 33.5 MB
  float* Sdt  = Fbuf + (size_t)BSZ * CHK * DM * DS;                  // 2 MB
  float* A2c  = Sdt + (size_t)BSZ * CHK * DM;                        // 64 KB
  float* A2t  = A2c + (size_t)DM * DS;                               // 64 KB
  float* cb2  = A2t + (size_t)DM * DS;                               // 64 KB

  hipLaunchKernelGGL(wprep_kernel, dim3(DM * DM / 1024), dim3(256), 0, stream,
                     dt_w, w_bf);
  hipLaunchKernelGGL(aprep_kernel, dim3(DM * DS / 256), dim3(256), 0, stream,
                     a_log, bm, cm, A2c, A2t, cb2);
  hipLaunchKernelGGL(conv_kernel, dim3(MROWS * DM / 1024), dim3(256), 0, stream,
                     x, cw, cb, xf_bf);
  hipLaunchKernelGGL(gemm_kernel, dim3(DM / 128, MROWS / 128), dim3(256), 0,
                     stream, xf_bf, w_bf, dt_b, ud);
  hipLaunchKernelGGL(scan_part1, dim3(DM / 256, CHK, BSZ), dim3(256), 0, stream,
                     ud, A2c, Fbuf, Sdt);
  hipLaunchKernelGGL(scan_combine, dim3(DM * DS / 256, BSZ), dim3(256), 0,
                     stream, Fbuf, Sdt, A2t);
  hipLaunchKernelGGL(scan_part3, dim3(DM / 256, CHK, BSZ), dim3(256), 0, stream,
                     ud, A2c, cb2, Fbuf, out);
}

// Round 5
// 288.959 us; speedup vs baseline: 3.6614x; 1.0292x over previous
//
#include <hip/hip_runtime.h>
#include <stdint.h>

#define BSZ 8
#define SEQ 2048
#define DM 1024
#define DS 16
#define MROWS (BSZ * SEQ)  // 16384
#define CHK 64             // chunks over SEQ
#define CLEN (SEQ / CHK)   // 32 steps per chunk
#define LOG2E 1.4426950408889634f

typedef __bf16 bf16x8 __attribute__((ext_vector_type(8)));
typedef float f32x4 __attribute__((ext_vector_type(4)));

union F4 { float4 v; float f[4]; };

// round-to-nearest-even fp32 -> bf16 (bit pattern)
__device__ __forceinline__ uint16_t f2bf(float f) {
  uint32_t u = __float_as_uint(f);
  u += 0x7FFFu + ((u >> 16) & 1u);
  return (uint16_t)(u >> 16);
}

// pack two floats as f16 pair in a uint32 (a = lo, b = hi)
__device__ __forceinline__ uint32_t pack_h2(float a, float b) {
  _Float16 ha = (_Float16)a, hb = (_Float16)b;
  uint16_t ua = __builtin_bit_cast(uint16_t, ha);
  uint16_t ub = __builtin_bit_cast(uint16_t, hb);
  return (uint32_t)ua | ((uint32_t)ub << 16);
}
__device__ __forceinline__ float unpack_lo(uint32_t v) {
  return (float)__builtin_bit_cast(_Float16, (uint16_t)(v & 0xffffu));
}
__device__ __forceinline__ float unpack_hi(uint32_t v) {
  return (float)__builtin_bit_cast(_Float16, (uint16_t)(v >> 16));
}

// async global->LDS, 16B per lane; LDS base must be wave-uniform.
__device__ __forceinline__ void async_cp16(const void* g, void* l) {
  __builtin_amdgcn_global_load_lds(
      (const __attribute__((address_space(1))) uint32_t*)(uintptr_t)g,
      (__attribute__((address_space(3))) uint32_t*)(uint32_t)(uintptr_t)l,
      16, 0, 0);
}

// ---------------- dt_w fp32 -> bf16 ----------------
__global__ __launch_bounds__(256) void wprep_kernel(
    const float* __restrict__ w, uint16_t* __restrict__ wb) {
  int t = blockIdx.x * 256 + threadIdx.x;  // DM*DM/4 threads
  F4 u; u.v = *(const float4*)(w + (size_t)t * 4);
  uint32_t lo = f2bf(u.f[0]) | ((uint32_t)f2bf(u.f[1]) << 16);
  uint32_t hi = f2bf(u.f[2]) | ((uint32_t)f2bf(u.f[3]) << 16);
  *(uint2*)(wb + (size_t)t * 4) = make_uint2(lo, hi);
}

// ---------------- scan parameter prep ----------------
__global__ __launch_bounds__(256) void aprep_kernel(
    const float* __restrict__ a_log, const float* __restrict__ bm,
    const float* __restrict__ cm, float* __restrict__ A2c,
    float* __restrict__ A2t, float* __restrict__ cb2) {
  int e = blockIdx.x * 256 + threadIdx.x;  // DM*DS threads
  float a = a_log[e];
  float A2 = -log1pf(__expf(a)) * LOG2E;
  A2c[e] = A2;
  cb2[e] = bm[e] * cm[e];
  int c = e >> 4, d = e & 15;
  int j = d >> 2, i = d & 3;
  A2t[((size_t)j * DM + c) * 4 + i] = A2;
}

// ---------------- depthwise conv k=3 pad=1 -> bf16 xf ----------------
__global__ __launch_bounds__(256) void conv_kernel(
    const float* __restrict__ x, const float* __restrict__ cw,
    const float* __restrict__ cb, uint16_t* __restrict__ xf) {
  int t = blockIdx.x * 256 + threadIdx.x;  // MROWS*DM/4 threads
  int cg = t & (DM / 4 - 1);
  int bn = t >> 8;
  int n = bn & (SEQ - 1);
  int c0 = cg * 4;
  const float* row = x + (size_t)bn * DM + c0;
  F4 xm, xc, xp;
  xm.v = make_float4(0.f, 0.f, 0.f, 0.f);
  xp.v = make_float4(0.f, 0.f, 0.f, 0.f);
  xc.v = *(const float4*)row;
  if (n > 0)       xm.v = *(const float4*)(row - DM);
  if (n < SEQ - 1) xp.v = *(const float4*)(row + DM);
  uint16_t o[4];
#pragma unroll
  for (int j = 0; j < 4; ++j) {
    int c = c0 + j;
    float v = cw[c * 3 + 0] * xm.f[j] + cw[c * 3 + 1] * xc.f[j] +
              cw[c * 3 + 2] * xp.f[j] + cb[c];
    o[j] = f2bf(v);
  }
  uint32_t lo = o[0] | ((uint32_t)o[1] << 16);
  uint32_t hi = o[2] | ((uint32_t)o[3] << 16);
  *(uint2*)(xf + (size_t)bn * DM + c0) = make_uint2(lo, hi);
}

// ---------------- dt GEMM + fused epilogue -> packed (u, dt) f16x2 ----------------
// NT GEMM, 128x128 tile, BK=64, 4 waves 2x2, 16x16x32 bf16 MFMA.
// LDS k-chunk XOR swizzle kills the 128B-stride bank conflict.
// Epilogue xf comes from a REGISTER STASH captured out of the As tile at
// kt == n0 + wn*64 (output cols index A's K dim) -> no global re-read of A.
__global__ __launch_bounds__(256) void gemm_kernel(
    const uint16_t* __restrict__ A,   // MROWS x DM bf16 (xf)
    const uint16_t* __restrict__ B,   // DM x DM bf16 (dt_w)
    const float* __restrict__ bias,   // DM (dt_b)
    uint32_t* __restrict__ ud) {      // MROWS x DM packed f16x2 (u, dt)
  __shared__ __align__(16) uint16_t As[128 * 64];
  __shared__ __align__(16) uint16_t Bs[128 * 64];
  const int tid = threadIdx.x;
  const int w = tid >> 6;
  const int L = tid & 63;
  const int wm = w & 1, wn = w >> 1;
  const int lane15 = L & 15, q = L >> 4;
  const int m0 = blockIdx.y * 128;
  const int n0 = blockIdx.x * 128;
  const int lr = L >> 3;                  // row-in-8 for staging
  const int lc = (((L & 7) ^ lr)) * 8;    // swizzled source k-chunk (8 bf16 = 16B)
  const int r7 = lane15 & 7;              // reader row&7

  f32x4 acc[4][4] = {};
  uint32_t xst[4][4][2];                  // [mi][ni][rpair]: bf16 r-even lo, r-odd hi
  const int ktmatch = n0 + wn * 64;       // wave-uniform

  for (int kt = 0; kt < DM; kt += 64) {
#pragma unroll
    for (int r = 0; r < 4; ++r) {
      int R = (r * 4 + w) * 8;  // wave-uniform LDS base
      async_cp16(A + (size_t)(m0 + R + lr) * DM + kt + lc, &As[R * 64]);
    }
#pragma unroll
    for (int r = 0; r < 4; ++r) {
      int R = (r * 4 + w) * 8;
      async_cp16(B + (size_t)(n0 + R + lr) * DM + kt + lc, &Bs[R * 64]);
    }
    __syncthreads();  // drains vmcnt -> LDS tiles visible

    if (kt == ktmatch) {  // wave-uniform branch: capture xf for the epilogue
#pragma unroll
      for (int mi = 0; mi < 4; ++mi)
#pragma unroll
        for (int ni = 0; ni < 4; ++ni)
#pragma unroll
          for (int rp = 0; rp < 2; ++rp) {
            int row0 = wm * 64 + mi * 16 + q * 4 + rp * 2;
            int row1 = row0 + 1;
            int cc = ni * 16 + lane15;  // in [0,64)
            uint32_t e0 = As[row0 * 64 + (((cc >> 3) ^ (row0 & 7)) << 3) + (cc & 7)];
            uint32_t e1 = As[row1 * 64 + (((cc >> 3) ^ (row1 & 7)) << 3) + (cc & 7)];
            xst[mi][ni][rp] = e0 | (e1 << 16);
          }
    }

#pragma unroll
    for (int ks = 0; ks < 64; ks += 32) {
      bf16x8 af[4], bfr[4];
      const int jbase = ks >> 3;
#pragma unroll
      for (int mi = 0; mi < 4; ++mi)
        af[mi] = *(const bf16x8*)(As + (wm * 64 + mi * 16 + lane15) * 64 +
                                  (((jbase + q) ^ r7) << 3));
#pragma unroll
      for (int ni = 0; ni < 4; ++ni)
        bfr[ni] = *(const bf16x8*)(Bs + (wn * 64 + ni * 16 + lane15) * 64 +
                                   (((jbase + q) ^ r7) << 3));
#pragma unroll
      for (int mi = 0; mi < 4; ++mi)
#pragma unroll
        for (int ni = 0; ni < 4; ++ni)
          acc[mi][ni] = __builtin_amdgcn_mfma_f32_16x16x32_bf16(
              af[mi], bfr[ni], acc[mi][ni], 0, 0, 0);
    }
    __syncthreads();
  }

  // epilogue: D layout col=lane&15, row=q*4+reg. sigmoid + u=dt*xf -> (u,dt) f16x2.
#pragma unroll
  for (int ni = 0; ni < 4; ++ni) {
    int col = n0 + wn * 64 + ni * 16 + lane15;
    float db = bias[col];
#pragma unroll
    for (int mi = 0; mi < 4; ++mi) {
      int rowb = m0 + wm * 64 + mi * 16 + q * 4;
#pragma unroll
      for (int r = 0; r < 4; ++r) {
        size_t idx = (size_t)(rowb + r) * DM + col;
        float z = acc[mi][ni][r] + db;
        float dtv = 0.099f / (1.f + __expf(-z)) + 0.001f;
        uint32_t p = xst[mi][ni][r >> 1];
        uint32_t bits = (r & 1) ? (p & 0xffff0000u) : (p << 16);
        float xfv = __uint_as_float(bits);
        ud[idx] = pack_h2(dtv * xfv, dtv);
      }
    }
  }
}

// ---------------- chunked selective scan (scaled state s~) ----------------
// lane = channel; one packed uint32 (u, dt) load per step.
// F layout d-plane-major: F[(((b*CHK+k)*4 + j)*DM + c)*4 + i], d = j*4+i.

__global__ __launch_bounds__(256) void scan_part1(
    const uint32_t* __restrict__ ud, const float* __restrict__ A2c,
    float* __restrict__ F, float* __restrict__ Sdt) {
  const int c = blockIdx.x * 256 + threadIdx.x;
  const int k = blockIdx.y;
  const int b = blockIdx.z;
  const int n0 = k * CLEN;

  float A2[DS], s[DS];
#pragma unroll
  for (int j = 0; j < 4; ++j) {
    F4 ua; ua.v = *(const float4*)(A2c + (size_t)c * DS + j * 4);
#pragma unroll
    for (int i = 0; i < 4; ++i) {
      A2[j * 4 + i] = ua.f[i];
      s[j * 4 + i] = 0.f;
    }
  }

  const uint32_t* up = ud + ((size_t)b * SEQ + n0) * DM + c;
  uint32_t c0 = up[0];
  uint32_t c1 = up[DM];
  uint32_t c2 = up[2 * DM];
  float sdt = 0.f;

#pragma unroll 4
  for (int t = 0; t < CLEN; ++t) {
    int tn = (t + 3 < CLEN) ? t + 3 : CLEN - 1;
    uint32_t c3 = up[(size_t)tn * DM];
    float uv = unpack_lo(c0);
    float dtv = unpack_hi(c0);
    sdt += dtv;
#pragma unroll
    for (int d = 0; d < DS; ++d) {
      float e = __builtin_amdgcn_exp2f(dtv * A2[d]);
      s[d] = fmaf(e, s[d], uv);
    }
    c0 = c1; c1 = c2; c2 = c3;
  }

  const size_t kk = (size_t)b * CHK + k;
#pragma unroll
  for (int j = 0; j < 4; ++j) {
    F4 fo;
#pragma unroll
    for (int i = 0; i < 4; ++i) fo.f[i] = s[j * 4 + i];
    *(float4*)(F + ((kk * 4 + j) * DM + c) * 4) = fo.v;
  }
  Sdt[kk * DM + c] = sdt;
}

// serial prefix over CHK chunks per (b,c,d); Sin (separate buffer, no alias)
// gets the carry-in for each chunk; F/Sdt prefetched one iteration ahead.
__global__ __launch_bounds__(256) void scan_combine(
    const float* __restrict__ F, float* __restrict__ Sin,
    const float* __restrict__ Sdt, const float* __restrict__ A2t) {
  const int t = blockIdx.x * 256 + threadIdx.x;  // flat (j,c,i)
  const int b = blockIdx.y;
  const int c = (t >> 2) & (DM - 1);
  const float A2 = A2t[t];
  const size_t stride = (size_t)DM * DS;
  const size_t base = (size_t)b * CHK * stride + t;
  const size_t sbase = (size_t)b * CHK * DM + c;
  float carry = 0.f;
  float fcur = F[base];
  float scur = Sdt[sbase];
#pragma unroll 4
  for (int k = 0; k < CHK; ++k) {
    int kn = (k + 1 < CHK) ? k + 1 : CHK - 1;
    float fnext = F[base + (size_t)kn * stride];
    float snext = Sdt[sbase + (size_t)kn * DM];
    float p = __builtin_amdgcn_exp2f(A2 * scur);
    Sin[base + (size_t)k * stride] = carry;
    carry = fmaf(p, carry, fcur);
    fcur = fnext; scur = snext;
  }
}

__global__ __launch_bounds__(256) void scan_part3(
    const uint32_t* __restrict__ ud, const float* __restrict__ A2c,
    const float* __restrict__ cb2m, const float* __restrict__ Sin,
    float* __restrict__ out) {
  const int c = blockIdx.x * 256 + threadIdx.x;
  const int k = blockIdx.y;
  const int b = blockIdx.z;
  const int n0 = k * CLEN;

  float A2[DS], cb2[DS], s[DS];
  const size_t kk = (size_t)b * CHK + k;
#pragma unroll
  for (int j = 0; j < 4; ++j) {
    F4 ua, uc, us;
    ua.v = *(const float4*)(A2c + (size_t)c * DS + j * 4);
    uc.v = *(const float4*)(cb2m + (size_t)c * DS + j * 4);
    us.v = *(const float4*)(Sin + ((kk * 4 + j) * DM + c) * 4);
#pragma unroll
    for (int i = 0; i < 4; ++i) {
      A2[j * 4 + i] = ua.f[i];
      cb2[j * 4 + i] = uc.f[i];
      s[j * 4 + i] = us.f[i];
    }
  }

  const uint32_t* up = ud + ((size_t)b * SEQ + n0) * DM + c;
  float* op = out + ((size_t)b * SEQ + n0) * DM + c;
  uint32_t c0 = up[0];
  uint32_t c1 = up[DM];
  uint32_t c2 = up[2 * DM];

#pragma unroll 4
  for (int t = 0; t < CLEN; ++t) {
    int tn = (t + 3 < CLEN) ? t + 3 : CLEN - 1;
    uint32_t c3 = up[(size_t)tn * DM];
    float uv = unpack_lo(c0);
    float dtv = unpack_hi(c0);
    float y0 = 0.f, y1 = 0.f;
#pragma unroll
    for (int d = 0; d < DS; d += 2) {
      float e0 = __builtin_amdgcn_exp2f(dtv * A2[d]);
      float e1 = __builtin_amdgcn_exp2f(dtv * A2[d + 1]);
      s[d] = fmaf(e0, s[d], uv);
      s[d + 1] = fmaf(e1, s[d + 1], uv);
      y0 = fmaf(cb2[d], s[d], y0);
      y1 = fmaf(cb2[d + 1], s[d + 1], y1);
    }
    op[(size_t)t * DM] = y0 + y1;
    c0 = c1; c1 = c2; c2 = c3;
  }
}

extern "C" void kernel_launch(void* const* d_in, const int* in_sizes, int n_in,
                              void* d_out, int out_size, void* d_ws, size_t ws_size,
                              hipStream_t stream) {
  const float* x     = (const float*)d_in[0];
  const float* a_log = (const float*)d_in[1];
  const float* bm    = (const float*)d_in[2];
  const float* cm    = (const float*)d_in[3];
  const float* dt_w  = (const float*)d_in[4];
  const float* dt_b  = (const float*)d_in[5];
  const float* cw    = (const float*)d_in[6];
  const float* cb    = (const float*)d_in[7];
  float* out = (float*)d_out;

  char* ws = (char*)d_ws;
  // region [0, 34MB): xf_bf (32MB) + w_bf (2MB) during conv/gemm;
  // REUSED as Sin (33.5MB) by combine/part3 (gemm completes first, stream order).
  uint16_t* xf_bf = (uint16_t*)ws;                                   // 32 MB
  uint16_t* w_bf  = (uint16_t*)(ws + (size_t)MROWS * DM * 2);        // 2 MB
  float*    Sin   = (float*)ws;                                      // 33.5 MB (alias)
  uint32_t* ud = (uint32_t*)(ws + (size_t)MROWS * DM * 2 + (size_t)DM * DM * 2);  // 64 MB
  float* Fbuf = (float*)(ud + (size_t)MROWS * DM);                   // 33.5 MB
  float* Sdt  = Fbuf + (size_t)BSZ * CHK * DM * DS;                  // 2 MB
  float* A2c  = Sdt + (size_t)BSZ * CHK * DM;                        // 64 KB
  float* A2t  = A2c + (size_t)DM * DS;                               // 64 KB
  float* cb2  = A2t + (size_t)DM * DS;                               // 64 KB

  hipLaunchKernelGGL(wprep_kernel, dim3(DM * DM / 1024), dim3(256), 0, stream,
                     dt_w, w_bf);
  hipLaunchKernelGGL(aprep_kernel, dim3(DM * DS / 256), dim3(256), 0, stream,
                     a_log, bm, cm, A2c, A2t, cb2);
  hipLaunchKernelGGL(conv_kernel, dim3(MROWS * DM / 1024), dim3(256), 0, stream,
                     x, cw, cb, xf_bf);
  hipLaunchKernelGGL(gemm_kernel, dim3(DM / 128, MROWS / 128), dim3(256), 0,
                     stream, xf_bf, w_bf, dt_b, ud);
  hipLaunchKernelGGL(scan_part1, dim3(DM / 256, CHK, BSZ), dim3(256), 0, stream,
                     ud, A2c, Fbuf, Sdt);
  hipLaunchKernelGGL(scan_combine, dim3(DM * DS / 256, BSZ), dim3(256), 0,
                     stream, Fbuf, Sin, Sdt, A2t);
  hipLaunchKernelGGL(scan_part3, dim3(DM / 256, CHK, BSZ), dim3(256), 0, stream,
                     ud, A2c, cb2, Sin, out);
}